// Round 5
// baseline (200.901 us; speedup 1.0000x reference)
//
#include <hip/hip_runtime.h>

typedef __bf16 bf16_t;
typedef __bf16 bf16x2 __attribute__((ext_vector_type(2)));
typedef __bf16 bf16x8 __attribute__((ext_vector_type(8)));
typedef float f32x4 __attribute__((ext_vector_type(4)));
typedef unsigned u32;
typedef unsigned u32x2 __attribute__((ext_vector_type(2)));
typedef unsigned u32x4 __attribute__((ext_vector_type(4)));

#define N_PIX 4096
#define CFEAT 256
#define CKEY 32
#define NBATCH 4

#if __has_builtin(__builtin_amdgcn_exp2f)
#define EXP2(x) __builtin_amdgcn_exp2f(x)
#else
#define EXP2(x) exp2f(x)
#endif

static __device__ __forceinline__ f32x4 mfma16(bf16x8 a, bf16x8 b, f32x4 c) {
    return __builtin_amdgcn_mfma_f32_16x16x32_bf16(a, b, c, 0, 0, 0);
}

// async global->LDS, 16B per lane; LDS dest = wave-uniform base + lane*16
static __device__ __forceinline__ void glds16(const void* g, void* l) {
    __builtin_amdgcn_global_load_lds(
        (const __attribute__((address_space(1))) void*)g,
        (__attribute__((address_space(3))) void*)l, 16, 0, 0);
}

// pack two f32 -> one dword of 2 bf16 (v_cvt_pk_bf16_f32)
static __device__ __forceinline__ u32 pk2(float lo, float hi) {
    bf16x2 t; t[0] = (bf16_t)lo; t[1] = (bf16_t)hi;
    return __builtin_bit_cast(u32, t);
}

// cast 8 consecutive f32 (two float4) -> bf16x8 fragment
static __device__ __forceinline__ bf16x8 cast8(const float* p) {
    f32x4 lo = *(const f32x4*)p;
    f32x4 hi = *(const f32x4*)(p + 4);
    u32x4 w = {pk2(lo[0], lo[1]), pk2(lo[2], lo[3]),
               pk2(hi[0], hi[1]), pk2(hi[2], hi[3])};
    return __builtin_bit_cast(bf16x8, w);
}

// 4-group transpose step (T12)
static __device__ __forceinline__ void xpose4(u32 &x, u32 &y) {
#if __has_builtin(__builtin_amdgcn_permlane32_swap) && __has_builtin(__builtin_amdgcn_permlane16_swap)
    auto r32 = __builtin_amdgcn_permlane32_swap(x, y, false, false);
    auto r16 = __builtin_amdgcn_permlane16_swap(r32[0], r32[1], false, false);
    x = r16[0]; y = r16[1];
#else
    const int lane = threadIdx.x & 63;
    const int g = lane >> 4, ln = lane & 15;
    const int i0 = ln + ((g & 1) << 5);
    const int i2 = i0 + 16;
    u32 xs0 = (u32)__shfl((int)x, i0), ys0 = (u32)__shfl((int)y, i0);
    u32 xs2 = (u32)__shfl((int)x, i2), ys2 = (u32)__shfl((int)y, i2);
    x = (g < 2) ? xs0 : ys0;
    y = (g < 2) ? xs2 : ys2;
#endif
}

// S^T tile (64 j x 16 i) -> exp2 -> in-register P fragments; l-sum via ones-MFMA.
static __device__ __forceinline__ void softmax_tile(
    const bf16x8 kf[4], bf16x8 qf, bf16x8 ones,
    f32x4 &accsum, bf16x8 &pa0, bf16x8 &pa1)
{
    f32x4 zero = {0.f, 0.f, 0.f, 0.f};
    f32x4 st[4];
#pragma unroll
    for (int jt = 0; jt < 4; ++jt) st[jt] = mfma16(kf[jt], qf, zero);
    float ex[16];
#pragma unroll
    for (int jt = 0; jt < 4; ++jt)
#pragma unroll
        for (int r = 0; r < 4; ++r) ex[jt * 4 + r] = EXP2(st[jt][r]);
    u32 a0 = pk2(ex[0],  ex[1]),  a1 = pk2(ex[2],  ex[3]);
    u32 b0 = pk2(ex[4],  ex[5]),  b1 = pk2(ex[6],  ex[7]);
    u32 c0 = pk2(ex[8],  ex[9]),  c1 = pk2(ex[10], ex[11]);
    u32 d0 = pk2(ex[12], ex[13]), d1 = pk2(ex[14], ex[15]);
    xpose4(a0, b0); xpose4(a1, b1);
    xpose4(c0, d0); xpose4(c1, d1);
    u32x4 w0 = {a0, a1, b0, b1};
    u32x4 w1 = {c0, c1, d0, d1};
    pa0 = __builtin_bit_cast(bf16x8, w0);
    pa1 = __builtin_bit_cast(bf16x8, w1);
    accsum = mfma16(ones, pa0, accsum);
    accsum = mfma16(ones, pa1, accsum);
}

// ---------------------------------------------------------------------------
// prep_kernel: transpose-cast cond & feat (f32 [c][n]) -> XT bf16 [n][c].
// XT lives in d_out (16 MB, exactly fits); pv overwrites d_out afterwards.
// grid 2048 x 256: bid>>10 = tensor, (bid>>8)&3 = batch, 64c x 64n tiles.
// ---------------------------------------------------------------------------
__global__ __launch_bounds__(256) void prep_kernel(
    const float* __restrict__ cond, const float* __restrict__ feat,
    bf16_t* __restrict__ XTc, bf16_t* __restrict__ XTf)
{
    __shared__ __attribute__((aligned(16))) float T[64][68];
    const int tid = threadIdx.x, bid = blockIdx.x;
    const int t = bid >> 10;
    const int r = bid & 1023;
    const int b = r >> 8;
    const int tile = r & 255;
    const int ct = tile >> 6, nt = tile & 63;
    const float* src = (t ? feat : cond) +
                       ((size_t)b * CFEAT + ct * 64) * N_PIX + (size_t)nt * 64;
    bf16_t* dst = (t ? XTf : XTc) +
                  ((size_t)b * N_PIX + nt * 64) * CFEAT + ct * 64;

    const int cl = tid >> 4, n4 = (tid & 15) * 4;
#pragma unroll
    for (int q = 0; q < 4; ++q) {
        f32x4 v = *(const f32x4*)&src[(size_t)(cl + q * 16) * N_PIX + n4];
        *(f32x4*)&T[cl + q * 16][n4] = v;
    }
    __syncthreads();
    const int n_loc = tid >> 2;
#pragma unroll
    for (int h = 0; h < 2; ++h) {
        const int c0 = (tid & 3) * 16 + h * 8;
        u32x4 o;
#pragma unroll
        for (int p = 0; p < 4; ++p)
            o[p] = pk2(T[c0 + 2 * p][n_loc], T[c0 + 2 * p + 1][n_loc]);
        *(u32x4*)&dst[(size_t)n_loc * CFEAT + c0] = o;
    }
}

// ---------------------------------------------------------------------------
// proj_kernel: Qt/Kt (transposed bf16, Q pre-scaled log2e) and V [c][n] bf16.
// A-frags: W f32 -> float4x2 + cvt_pk inline. B-frags: single 16B bf16 load
// from XT (k-contiguous). blocks [0,256)=Q, [256,512)=K, [512,1024)=V.
// ---------------------------------------------------------------------------
__global__ __launch_bounds__(256) void proj_kernel(
    const float* __restrict__ Wq, const float* __restrict__ bq,
    const float* __restrict__ Wk, const float* __restrict__ bk,
    const float* __restrict__ Wv, const float* __restrict__ bv,
    const bf16_t* __restrict__ XTc, const bf16_t* __restrict__ XTf,
    bf16_t* __restrict__ Qt, bf16_t* __restrict__ Kt, bf16_t* __restrict__ Vv)
{
    __shared__ __attribute__((aligned(16))) bf16_t T[64][40];  // QK repack
    const int lane = threadIdx.x & 63, wave = threadIdx.x >> 6;
    const int g = lane >> 4, ln = lane & 15;
    const int bid = blockIdx.x;
    f32x4 zero = {0.f, 0.f, 0.f, 0.f};

    if (bid < 512) {
        const bool isK = (bid >= 256);
        const int idx = bid & 255;
        const int xt = idx & 63;
        const int b  = idx >> 6;
        const float* W    = isK ? Wk : Wq;
        const float* bias = isK ? bk : bq;
        const bf16_t* XT = (isK ? XTf : XTc) + (size_t)b * N_PIX * CFEAT;
        bf16_t* Yt = (isK ? Kt : Qt) + (size_t)b * N_PIX * CKEY;
        const float qscale = isK ? 1.0f : 1.4426950408889634f;

        const int m_base = (wave & 1) * 16;
        const int n_loc  = (wave >> 1) * 32;
        const int n_base = xt * 64 + n_loc;

        f32x4 acc[2] = {zero, zero};
#pragma unroll
        for (int k0 = 0; k0 < CFEAT; k0 += 32) {
            bf16x8 a = cast8(W + (size_t)(m_base + ln) * CFEAT + k0 + g * 8);
#pragma unroll
            for (int nt = 0; nt < 2; ++nt) {
                bf16x8 bfr = *(const bf16x8*)
                    &XT[(size_t)(n_base + nt * 16 + ln) * CFEAT + k0 + g * 8];
                acc[nt] = mfma16(a, bfr, acc[nt]);
            }
        }
#pragma unroll
        for (int nt = 0; nt < 2; ++nt)
#pragma unroll
            for (int r = 0; r < 4; ++r) {
                const int ck = m_base + g * 4 + r;
                T[n_loc + nt * 16 + ln][ck] = (bf16_t)((acc[nt][r] + bias[ck]) * qscale);
            }
        __syncthreads();
        const int n  = threadIdx.x >> 2;
        const int sg = threadIdx.x & 3;
        bf16x8 row = *(const bf16x8*)&T[n][sg * 8];
        *(bf16x8*)&Yt[(size_t)(xt * 64 + n) * CKEY + sg * 8] = row;
    } else {
        const int idx = bid - 512;
        const int xt = idx & 127;
        const int b  = idx >> 7;
        const int n_base = xt * 32;
        const int c_wave = wave * 64;
        const bf16_t* XT = XTf + (size_t)b * N_PIX * CFEAT;
        bf16_t* Vb = Vv + (size_t)b * CFEAT * N_PIX;

        f32x4 acc[4][2];
#pragma unroll
        for (int mt = 0; mt < 4; ++mt) { acc[mt][0] = zero; acc[mt][1] = zero; }

#pragma unroll
        for (int k0 = 0; k0 < CFEAT; k0 += 32) {
            bf16x8 bfr[2];
#pragma unroll
            for (int nt = 0; nt < 2; ++nt)
                bfr[nt] = *(const bf16x8*)
                    &XT[(size_t)(n_base + nt * 16 + ln) * CFEAT + k0 + g * 8];
#pragma unroll
            for (int mt = 0; mt < 4; ++mt) {
                bf16x8 a = cast8(Wv + (size_t)(c_wave + mt * 16 + ln) * CFEAT + k0 + g * 8);
                acc[mt][0] = mfma16(a, bfr[0], acc[mt][0]);
                acc[mt][1] = mfma16(a, bfr[1], acc[mt][1]);
            }
        }
#pragma unroll
        for (int mt = 0; mt < 4; ++mt)
#pragma unroll
            for (int nt = 0; nt < 2; ++nt)
#pragma unroll
                for (int r = 0; r < 4; ++r) {
                    const int m = c_wave + mt * 16 + g * 4 + r;
                    const int n = n_base + nt * 16 + ln;
                    Vb[(size_t)m * N_PIX + n] = (bf16_t)(acc[mt][nt][r] + bv[m]);
                }
    }
}

// ---------------------------------------------------------------------------
// pv: out = gamma * softmax(QK^T) V / l + features (max-free softmax).
// i_per_wave 16 -> 32 (halves LDS read traffic, the measured bottleneck):
//   - block = 2 waves (128 thr), each wave: 128c x 32i (two 16-i subtiles
//     sharing every V A-fragment). grid (2, 64, 4) = 512 blocks = 2/CU.
//   - 4-deep V ring (4 x 16KB = 64KB LDS), stage distance 2, counted
//     vmcnt(8) fence + raw s_barrier (stage(n+2) stays in flight).
//   - K loads at iteration top (L2-resident), consumed same iter; softmax's
//     implicit kf-wait (vmcnt<=8) also retires stage(n+1) for free.
//   - P in registers (cvt_pk + permlane); l-sum via ones-MFMA per subtile.
// ---------------------------------------------------------------------------
__global__ __launch_bounds__(128, 1) void pv_kernel(
    const bf16_t* __restrict__ Qt, const bf16_t* __restrict__ Kt,
    const bf16_t* __restrict__ V,
    const float* __restrict__ features, const float* __restrict__ gamma,
    float* __restrict__ out)
{
    __shared__ __attribute__((aligned(16))) bf16_t Vlds[4][128 * 64];  // 64KB ring

    const int lane = threadIdx.x & 63, wave = threadIdx.x >> 6;  // wave 0/1
    const int g = lane >> 4, ln = lane & 15;
    const int b = blockIdx.z;
    const int i_base = blockIdx.y * 64 + wave * 32;
    const int c_base = blockIdx.x * 128;

    const bf16_t* Qb = Qt + (size_t)b * N_PIX * CKEY;
    const bf16_t* Kb = Kt + (size_t)b * N_PIX * CKEY;
    const bf16_t* Vb = V + (size_t)b * CFEAT * N_PIX;

    // staging: 1024 slots/tile; this thread's 8 slots s = wave*512 + q*64 + lane
    const bf16_t* vgp[8];
#pragma unroll
    for (int q = 0; q < 8; ++q) {
        const int s = wave * 512 + q * 64 + lane;
        const int sc = s >> 3, sj = (s & 7) ^ (sc & 7);
        vgp[q] = Vb + (size_t)(c_base + sc) * N_PIX + sj * 8;
    }

    const bf16x8 qf0 = *(const bf16x8*)&Qb[(size_t)(i_base + ln) * CKEY + g * 8];
    const bf16x8 qf1 = *(const bf16x8*)&Qb[(size_t)(i_base + 16 + ln) * CKEY + g * 8];

    bf16x8 ones;
#pragma unroll
    for (int j = 0; j < 8; ++j) ones[j] = (bf16_t)1.0f;

    f32x4 zero = {0.f, 0.f, 0.f, 0.f};
    f32x4 acc[8][2];
#pragma unroll
    for (int ct = 0; ct < 8; ++ct) { acc[ct][0] = zero; acc[ct][1] = zero; }
    f32x4 accsum0 = zero, accsum1 = zero;

    bf16x8 pa0c0, pa1c0, pa0c1, pa1c1;

    // ---------------- prologue: K(0); stage tiles 0,1; P(0) ----------------
    {
        bf16x8 kf[4];
#pragma unroll
        for (int jt = 0; jt < 4; ++jt)
            kf[jt] = *(const bf16x8*)&Kb[(size_t)(jt * 16 + ln) * CKEY + g * 8];
        asm volatile("" ::: "memory");   // K before the DMAs (vmcnt bookkeeping)
#pragma unroll
        for (int q = 0; q < 8; ++q)
            glds16(vgp[q], &Vlds[0][(wave * 512 + q * 64) * 8]);
#pragma unroll
        for (int q = 0; q < 8; ++q)
            glds16(vgp[q] + 64, &Vlds[1][(wave * 512 + q * 64) * 8]);
        softmax_tile(kf, qf0, ones, accsum0, pa0c0, pa1c0);
        softmax_tile(kf, qf1, ones, accsum1, pa0c1, pa1c1);
        asm volatile("s_waitcnt vmcnt(8)" ::: "memory");  // stage(0) done
        __builtin_amdgcn_s_barrier();
        asm volatile("" ::: "memory");
    }

    for (int n = 0; n < 64; ++n) {
        // ---- K(n+1) first (L2 latency hides under the ds_reads below) ----
        const int jq = ((n + 1) & 63) * 64;
        bf16x8 kf[4];
#pragma unroll
        for (int jt = 0; jt < 4; ++jt)
            kf[jt] = *(const bf16x8*)&Kb[(size_t)(jq + jt * 16 + ln) * CKEY + g * 8];

        // ---- V fragments for tile n (buf guaranteed by previous barrier) ----
        const bf16_t* Vt = &Vlds[n & 3][0];
        bf16x8 vf[16];
#pragma unroll
        for (int ct = 0; ct < 8; ++ct) {
            const int c = ct * 16 + ln;
            vf[2 * ct]     = *(const bf16x8*)&Vt[(c * 8 + ( g      ^ (c & 7))) * 8];
            vf[2 * ct + 1] = *(const bf16x8*)&Vt[(c * 8 + ((4 + g) ^ (c & 7))) * 8];
        }
        asm volatile("" ::: "memory");   // K loads stay BEFORE the stage DMAs

        // ---- stage tile n+2 ----
        const int jn = (n * 64 + 128) & (N_PIX - 1);
        bf16_t* ldb = &Vlds[(n + 2) & 3][0];
#pragma unroll
        for (int q = 0; q < 8; ++q)
            glds16(vgp[q] + jn, &ldb[(wave * 512 + q * 64) * 8]);

        // ---- P(n+1): two 16-i subtiles (implicit kf-wait leaves stage(n+2)) ----
        bf16x8 pa0n0, pa1n0, pa0n1, pa1n1;
        const bool live = (n < 63);
        if (live) {
            softmax_tile(kf, qf0, ones, accsum0, pa0n0, pa1n0);
            softmax_tile(kf, qf1, ones, accsum1, pa0n1, pa1n1);
        }

        // ---- counted fence + barrier: stage(n+1) done, stage(n+2) in flight ----
        asm volatile("s_waitcnt vmcnt(8)" ::: "memory");
        __builtin_amdgcn_s_barrier();
        asm volatile("" ::: "memory");

        // ---- PV(n): each V fragment feeds BOTH i-subtiles ----
        __builtin_amdgcn_s_setprio(1);
#pragma unroll
        for (int ct = 0; ct < 8; ++ct) {
            acc[ct][0] = mfma16(vf[2 * ct],     pa0c0, acc[ct][0]);
            acc[ct][0] = mfma16(vf[2 * ct + 1], pa1c0, acc[ct][0]);
            acc[ct][1] = mfma16(vf[2 * ct],     pa0c1, acc[ct][1]);
            acc[ct][1] = mfma16(vf[2 * ct + 1], pa1c1, acc[ct][1]);
        }
        __builtin_amdgcn_s_setprio(0);
        if (live) {
            pa0c0 = pa0n0; pa1c0 = pa1n0;
            pa0c1 = pa0n1; pa1c1 = pa1n1;
        }
    }

    const float s0 = gamma[0] / accsum0[0];
    const float s1 = gamma[0] / accsum1[0];

#pragma unroll
    for (int ct = 0; ct < 8; ++ct)
#pragma unroll
        for (int r = 0; r < 4; ++r) {
            const int c = c_base + ct * 16 + g * 4 + r;
            const size_t row = ((size_t)b * CFEAT + c) * N_PIX;
            const size_t idx0 = row + i_base + ln;
            const size_t idx1 = row + i_base + 16 + ln;
            out[idx0] = s0 * acc[ct][0][r] + features[idx0];
            out[idx1] = s1 * acc[ct][1][r] + features[idx1];
        }
}

// ---------------------------------------------------------------------------
extern "C" void kernel_launch(void* const* d_in, const int* in_sizes, int n_in,
                              void* d_out, int out_size, void* d_ws, size_t ws_size,
                              hipStream_t stream) {
    const float* features   = (const float*)d_in[0];
    const float* conditions = (const float*)d_in[1];
    const float* Wq  = (const float*)d_in[2];
    const float* bq  = (const float*)d_in[3];
    const float* Wk  = (const float*)d_in[4];
    const float* bk  = (const float*)d_in[5];
    const float* Wv  = (const float*)d_in[6];
    const float* bv  = (const float*)d_in[7];
    const float* gam = (const float*)d_in[8];
    float* out = (float*)d_out;

    // ws (bf16): Qt 1MB | Kt 1MB | V 8MB
    bf16_t* Qt = (bf16_t*)d_ws;
    bf16_t* Kt = Qt + (size_t)NBATCH * N_PIX * CKEY;
    bf16_t* Vw = Kt + (size_t)NBATCH * N_PIX * CKEY;
    // XT (bf16 [b][n][c]) staged in d_out (16 MB, exact fit); pv overwrites it.
    bf16_t* XTc = (bf16_t*)d_out;
    bf16_t* XTf = XTc + (size_t)NBATCH * N_PIX * CFEAT;

    prep_kernel<<<dim3(2048, 1, 1), 256, 0, stream>>>(conditions, features, XTc, XTf);
    proj_kernel<<<dim3(1024, 1, 1), 256, 0, stream>>>(
        Wq, bq, Wk, bk, Wv, bv, XTc, XTf, Qt, Kt, Vw);
    pv_kernel<<<dim3(2, N_PIX / 64, NBATCH), 128, 0, stream>>>(
        Qt, Kt, Vw, features, gam, out);
}

// Round 6
// 175.994 us; speedup vs baseline: 1.1415x; 1.1415x over previous
//
#include <hip/hip_runtime.h>

typedef __bf16 bf16_t;
typedef __bf16 bf16x2 __attribute__((ext_vector_type(2)));
typedef __bf16 bf16x8 __attribute__((ext_vector_type(8)));
typedef float f32x4 __attribute__((ext_vector_type(4)));
typedef unsigned u32;
typedef unsigned u32x4 __attribute__((ext_vector_type(4)));

#define N_PIX 4096
#define CFEAT 256
#define CKEY 32
#define NBATCH 4

#if __has_builtin(__builtin_amdgcn_exp2f)
#define EXP2(x) __builtin_amdgcn_exp2f(x)
#else
#define EXP2(x) exp2f(x)
#endif

static __device__ __forceinline__ f32x4 mfma16(bf16x8 a, bf16x8 b, f32x4 c) {
    return __builtin_amdgcn_mfma_f32_16x16x32_bf16(a, b, c, 0, 0, 0);
}

// async global->LDS, 16B per lane; LDS dest = wave-uniform base + lane*16
static __device__ __forceinline__ void glds16(const void* g, void* l) {
    __builtin_amdgcn_global_load_lds(
        (const __attribute__((address_space(1))) void*)g,
        (__attribute__((address_space(3))) void*)l, 16, 0, 0);
}

// pack two f32 -> one dword of 2 bf16 (v_cvt_pk_bf16_f32)
static __device__ __forceinline__ u32 pk2(float lo, float hi) {
    bf16x2 t; t[0] = (bf16_t)lo; t[1] = (bf16_t)hi;
    return __builtin_bit_cast(u32, t);
}

// cast 8 consecutive f32 (two float4) -> bf16x8 fragment
static __device__ __forceinline__ bf16x8 cast8(const float* p) {
    f32x4 lo = *(const f32x4*)p;
    f32x4 hi = *(const f32x4*)(p + 4);
    u32x4 w = {pk2(lo[0], lo[1]), pk2(lo[2], lo[3]),
               pk2(hi[0], hi[1]), pk2(hi[2], hi[3])};
    return __builtin_bit_cast(bf16x8, w);
}

// 4-group transpose step (T12)
static __device__ __forceinline__ void xpose4(u32 &x, u32 &y) {
#if __has_builtin(__builtin_amdgcn_permlane32_swap) && __has_builtin(__builtin_amdgcn_permlane16_swap)
    auto r32 = __builtin_amdgcn_permlane32_swap(x, y, false, false);
    auto r16 = __builtin_amdgcn_permlane16_swap(r32[0], r32[1], false, false);
    x = r16[0]; y = r16[1];
#else
    const int lane = threadIdx.x & 63;
    const int g = lane >> 4, ln = lane & 15;
    const int i0 = ln + ((g & 1) << 5);
    const int i2 = i0 + 16;
    u32 xs0 = (u32)__shfl((int)x, i0), ys0 = (u32)__shfl((int)y, i0);
    u32 xs2 = (u32)__shfl((int)x, i2), ys2 = (u32)__shfl((int)y, i2);
    x = (g < 2) ? xs0 : ys0;
    y = (g < 2) ? xs2 : ys2;
#endif
}

// S^T tile (64 j x 16 i) -> exp2 -> in-register P fragments; l-sum via ones-MFMA.
static __device__ __forceinline__ void softmax_tile(
    const bf16x8 kf[4], bf16x8 qf, bf16x8 ones,
    f32x4 &accsum, bf16x8 &pa0, bf16x8 &pa1)
{
    f32x4 zero = {0.f, 0.f, 0.f, 0.f};
    f32x4 st[4];
#pragma unroll
    for (int jt = 0; jt < 4; ++jt) st[jt] = mfma16(kf[jt], qf, zero);
    float ex[16];
#pragma unroll
    for (int jt = 0; jt < 4; ++jt)
#pragma unroll
        for (int r = 0; r < 4; ++r) ex[jt * 4 + r] = EXP2(st[jt][r]);
    u32 a0 = pk2(ex[0],  ex[1]),  a1 = pk2(ex[2],  ex[3]);
    u32 b0 = pk2(ex[4],  ex[5]),  b1 = pk2(ex[6],  ex[7]);
    u32 c0 = pk2(ex[8],  ex[9]),  c1 = pk2(ex[10], ex[11]);
    u32 d0 = pk2(ex[12], ex[13]), d1 = pk2(ex[14], ex[15]);
    xpose4(a0, b0); xpose4(a1, b1);
    xpose4(c0, d0); xpose4(c1, d1);
    u32x4 w0 = {a0, a1, b0, b1};
    u32x4 w1 = {c0, c1, d0, d1};
    pa0 = __builtin_bit_cast(bf16x8, w0);
    pa1 = __builtin_bit_cast(bf16x8, w1);
    accsum = mfma16(ones, pa0, accsum);
    accsum = mfma16(ones, pa1, accsum);
}

// ---------------------------------------------------------------------------
// prep_kernel: transpose-cast cond & feat (f32 [c][n]) -> XT bf16 [n][c].
// XT lives in d_out (16 MB, exact fit); pv overwrites d_out afterwards.
// ---------------------------------------------------------------------------
__global__ __launch_bounds__(256) void prep_kernel(
    const float* __restrict__ cond, const float* __restrict__ feat,
    bf16_t* __restrict__ XTc, bf16_t* __restrict__ XTf)
{
    __shared__ __attribute__((aligned(16))) float T[64][68];
    const int tid = threadIdx.x, bid = blockIdx.x;
    const int t = bid >> 10;
    const int r = bid & 1023;
    const int b = r >> 8;
    const int tile = r & 255;
    const int ct = tile >> 6, nt = tile & 63;
    const float* src = (t ? feat : cond) +
                       ((size_t)b * CFEAT + ct * 64) * N_PIX + (size_t)nt * 64;
    bf16_t* dst = (t ? XTf : XTc) +
                  ((size_t)b * N_PIX + nt * 64) * CFEAT + ct * 64;

    const int cl = tid >> 4, n4 = (tid & 15) * 4;
#pragma unroll
    for (int q = 0; q < 4; ++q) {
        f32x4 v = *(const f32x4*)&src[(size_t)(cl + q * 16) * N_PIX + n4];
        *(f32x4*)&T[cl + q * 16][n4] = v;
    }
    __syncthreads();
    const int n_loc = tid >> 2;
#pragma unroll
    for (int h = 0; h < 2; ++h) {
        const int c0 = (tid & 3) * 16 + h * 8;
        u32x4 o;
#pragma unroll
        for (int p = 0; p < 4; ++p)
            o[p] = pk2(T[c0 + 2 * p][n_loc], T[c0 + 2 * p + 1][n_loc]);
        *(u32x4*)&dst[(size_t)n_loc * CFEAT + c0] = o;
    }
}

// ---------------------------------------------------------------------------
// proj_kernel: Qt/Kt (transposed bf16, Q pre-scaled log2e) and V [c][n] bf16.
// (R5 structure; k0 loops NOT unrolled — R5's unroll was a VGPR-pressure risk)
// ---------------------------------------------------------------------------
__global__ __launch_bounds__(256) void proj_kernel(
    const float* __restrict__ Wq, const float* __restrict__ bq,
    const float* __restrict__ Wk, const float* __restrict__ bk,
    const float* __restrict__ Wv, const float* __restrict__ bv,
    const bf16_t* __restrict__ XTc, const bf16_t* __restrict__ XTf,
    bf16_t* __restrict__ Qt, bf16_t* __restrict__ Kt, bf16_t* __restrict__ Vv)
{
    __shared__ __attribute__((aligned(16))) bf16_t T[64][40];  // QK repack
    const int lane = threadIdx.x & 63, wave = threadIdx.x >> 6;
    const int g = lane >> 4, ln = lane & 15;
    const int bid = blockIdx.x;
    f32x4 zero = {0.f, 0.f, 0.f, 0.f};

    if (bid < 512) {
        const bool isK = (bid >= 256);
        const int idx = bid & 255;
        const int xt = idx & 63;
        const int b  = idx >> 6;
        const float* W    = isK ? Wk : Wq;
        const float* bias = isK ? bk : bq;
        const bf16_t* XT = (isK ? XTf : XTc) + (size_t)b * N_PIX * CFEAT;
        bf16_t* Yt = (isK ? Kt : Qt) + (size_t)b * N_PIX * CKEY;
        const float qscale = isK ? 1.0f : 1.4426950408889634f;

        const int m_base = (wave & 1) * 16;
        const int n_loc  = (wave >> 1) * 32;
        const int n_base = xt * 64 + n_loc;

        f32x4 acc[2] = {zero, zero};
        for (int k0 = 0; k0 < CFEAT; k0 += 32) {
            bf16x8 a = cast8(W + (size_t)(m_base + ln) * CFEAT + k0 + g * 8);
#pragma unroll
            for (int nt = 0; nt < 2; ++nt) {
                bf16x8 bfr = *(const bf16x8*)
                    &XT[(size_t)(n_base + nt * 16 + ln) * CFEAT + k0 + g * 8];
                acc[nt] = mfma16(a, bfr, acc[nt]);
            }
        }
#pragma unroll
        for (int nt = 0; nt < 2; ++nt)
#pragma unroll
            for (int r = 0; r < 4; ++r) {
                const int ck = m_base + g * 4 + r;
                T[n_loc + nt * 16 + ln][ck] = (bf16_t)((acc[nt][r] + bias[ck]) * qscale);
            }
        __syncthreads();
        const int n  = threadIdx.x >> 2;
        const int sg = threadIdx.x & 3;
        bf16x8 row = *(const bf16x8*)&T[n][sg * 8];
        *(bf16x8*)&Yt[(size_t)(xt * 64 + n) * CKEY + sg * 8] = row;
    } else {
        const int idx = bid - 512;
        const int xt = idx & 127;
        const int b  = idx >> 7;
        const int n_base = xt * 32;
        const int c_wave = wave * 64;
        const bf16_t* XT = XTf + (size_t)b * N_PIX * CFEAT;
        bf16_t* Vb = Vv + (size_t)b * CFEAT * N_PIX;

        f32x4 acc[4][2];
#pragma unroll
        for (int mt = 0; mt < 4; ++mt) { acc[mt][0] = zero; acc[mt][1] = zero; }

        for (int k0 = 0; k0 < CFEAT; k0 += 32) {
            bf16x8 bfr[2];
#pragma unroll
            for (int nt = 0; nt < 2; ++nt)
                bfr[nt] = *(const bf16x8*)
                    &XT[(size_t)(n_base + nt * 16 + ln) * CFEAT + k0 + g * 8];
#pragma unroll
            for (int mt = 0; mt < 4; ++mt) {
                bf16x8 a = cast8(Wv + (size_t)(c_wave + mt * 16 + ln) * CFEAT + k0 + g * 8);
                acc[mt][0] = mfma16(a, bfr[0], acc[mt][0]);
                acc[mt][1] = mfma16(a, bfr[1], acc[mt][1]);
            }
        }
#pragma unroll
        for (int mt = 0; mt < 4; ++mt)
#pragma unroll
            for (int nt = 0; nt < 2; ++nt)
#pragma unroll
                for (int r = 0; r < 4; ++r) {
                    const int m = c_wave + mt * 16 + g * 4 + r;
                    const int n = n_base + nt * 16 + ln;
                    Vb[(size_t)m * N_PIX + n] = (bf16_t)(acc[mt][nt][r] + bv[m]);
                }
    }
}

// ---------------------------------------------------------------------------
// pv v3: 8-wave producer/consumer block, full 256c x 64i (c-split removed).
//   - waves 0-3 (sm): softmax for 16i each -> P tile to swizzled ping-pong
//     Plds (byte = i*128 + ((j>>3)^(i&7))*16; write AND read <=2-way banks).
//   - all 8 waves: PV on a private 32c slice (V frags 4 reads, P frags 8).
//   - ring-4 V (4 x 32KB), stage dist 2, K prefetch dist 2 (ping-pong).
//   - UNIFORM vmcnt(6) fence: sm waves issue 4K+2stage, pv waves 6stage/iter.
//   - single s_barrier per iter (lgkmcnt(0) publishes P before it).
// grid (64 i-tiles, 4 b) = 256 blocks = 1/CU; 8 waves = 2/SIMD.
// ---------------------------------------------------------------------------
__global__ __launch_bounds__(512, 2) void pv_kernel(
    const bf16_t* __restrict__ Qt, const bf16_t* __restrict__ Kt,
    const bf16_t* __restrict__ V,
    const float* __restrict__ features, const float* __restrict__ gamma,
    float* __restrict__ out)
{
    __shared__ __attribute__((aligned(16))) bf16_t Vlds[4][16384];  // 4 x 32KB
    __shared__ __attribute__((aligned(16))) bf16_t Plds[2][4096];   // 2 x 8KB
    __shared__ float Llds[64];

    const int lane = threadIdx.x & 63, wave = threadIdx.x >> 6;  // 0..7
    const int g = lane >> 4, ln = lane & 15;
    const int b = blockIdx.y;
    const int i_base = blockIdx.x * 64;
    const bool sm = (wave < 4);

    const bf16_t* Qb = Qt + (size_t)b * N_PIX * CKEY;
    const bf16_t* Kb = Kt + (size_t)b * N_PIX * CKEY;
    const bf16_t* Vb = V + (size_t)b * CFEAT * N_PIX;

    // staging units (32 per tile): sm waves 2 each, pv waves 6 each
    const int u0 = sm ? wave * 2 : 8 + (wave - 4) * 6;
    const bf16_t* vgp[6];
#pragma unroll
    for (int q = 0; q < 6; ++q) {
        const int s = (u0 + q) * 64 + lane;
        const int sc = s >> 3, sj = (s & 7) ^ (sc & 7);
        vgp[q] = Vb + (size_t)sc * N_PIX + sj * 8;
    }

#define STAGE(BUF, JOFF)                                                     \
    if (sm) {                                                                \
        _Pragma("unroll") for (int q = 0; q < 2; ++q)                        \
            glds16(vgp[q] + (JOFF), &Vlds[BUF][(u0 + q) * 512]);             \
    } else {                                                                 \
        _Pragma("unroll") for (int q = 0; q < 6; ++q)                        \
            glds16(vgp[q] + (JOFF), &Vlds[BUF][(u0 + q) * 512]);             \
    }

#define LOADK(DST, JQ)                                                       \
    { _Pragma("unroll") for (int jt = 0; jt < 4; ++jt)                       \
        DST[jt] = *(const bf16x8*)&Kb[(size_t)((JQ) + jt * 16 + ln) * CKEY + g * 8]; }

#define PWRITE(SLOT, PA0, PA1)                                               \
    { const int ir = wave * 16 + ln;                                         \
      char* Pw = (char*)&Plds[SLOT][0] + ir * 128;                           \
      *(bf16x8*)(Pw + ((g)     ^ (ir & 7)) * 16) = PA0;                      \
      *(bf16x8*)(Pw + ((4 + g) ^ (ir & 7)) * 16) = PA1; }

    bf16x8 qf = {};
    if (sm) qf = *(const bf16x8*)&Qb[(size_t)(i_base + wave * 16 + ln) * CKEY + g * 8];

    bf16x8 ones;
#pragma unroll
    for (int j = 0; j < 8; ++j) ones[j] = (bf16_t)1.0f;

    f32x4 zero = {0.f, 0.f, 0.f, 0.f};
    f32x4 acc[2][4];
#pragma unroll
    for (int ct = 0; ct < 2; ++ct)
#pragma unroll
        for (int it = 0; it < 4; ++it) acc[ct][it] = zero;
    f32x4 accsum = zero;

    bf16x8 kfA[4], kfB[4];

    // ---------------- prologue: P(0); stage V(0),V(1); kfA = K(1) ----------
    if (sm) LOADK(kfA, 0);
    asm volatile("" ::: "memory");
    STAGE(0, 0);
    STAGE(1, 64);
    if (sm) {
        bf16x8 pa0, pa1;
        softmax_tile(kfA, qf, ones, accsum, pa0, pa1);
        PWRITE(0, pa0, pa1);
        LOADK(kfA, 64);
    }
    __syncthreads();   // prologue-only full drain (vm + lgkm)

// iter n: read V(n)+P(n) frags; sm: issue K(n+2), softmax K(n+1)->P(n+1);
// all: stage V(n+2); uniform vmcnt(6)+lgkmcnt(0)+barrier; PV(n) MFMAs.
#define PV_ITER(NN, KU, KN)                                                  \
  {                                                                          \
    const int nn = (NN);                                                     \
    const bf16_t* Vt = &Vlds[nn & 3][0];                                     \
    bf16x8 vf[4];                                                            \
    _Pragma("unroll")                                                        \
    for (int ct = 0; ct < 2; ++ct)                                           \
      _Pragma("unroll")                                                      \
      for (int s = 0; s < 2; ++s) {                                          \
        const int c = wave * 32 + ct * 16 + ln;                              \
        vf[ct * 2 + s] = *(const bf16x8*)&Vt[(c * 8 + ((s * 4 + g) ^ (c & 7))) * 8]; \
      }                                                                      \
    const char* Pr = (const char*)&Plds[nn & 1][0];                          \
    bf16x8 pf[8];                                                            \
    _Pragma("unroll")                                                        \
    for (int it = 0; it < 4; ++it)                                           \
      _Pragma("unroll")                                                      \
      for (int s = 0; s < 2; ++s)                                            \
        pf[it * 2 + s] = *(const bf16x8*)(Pr + (it * 16 + ln) * 128          \
                           + ((s * 4 + g) ^ (ln & 7)) * 16);                 \
    const bool live = (nn < 63);                                             \
    if (sm && live) LOADK(KN, ((nn + 2) & 63) * 64);                         \
    asm volatile("" ::: "memory");  /* K loads stay BEFORE the stage DMAs */ \
    STAGE((nn + 2) & 3, ((nn * 64 + 128) & (N_PIX - 1)));                    \
    if (sm && live) {                                                        \
      bf16x8 pa0, pa1;                                                       \
      softmax_tile(KU, qf, ones, accsum, pa0, pa1);                          \
      PWRITE((nn + 1) & 1, pa0, pa1);                                        \
    }                                                                        \
    asm volatile("s_waitcnt vmcnt(6)" ::: "memory");                         \
    asm volatile("s_waitcnt lgkmcnt(0)" ::: "memory");                       \
    __builtin_amdgcn_s_barrier();                                            \
    asm volatile("" ::: "memory");                                           \
    __builtin_amdgcn_s_setprio(1);                                           \
    _Pragma("unroll")                                                        \
    for (int ct = 0; ct < 2; ++ct)                                           \
      _Pragma("unroll")                                                      \
      for (int it = 0; it < 4; ++it) {                                       \
        acc[ct][it] = mfma16(vf[ct * 2 + 0], pf[it * 2 + 0], acc[ct][it]);   \
        acc[ct][it] = mfma16(vf[ct * 2 + 1], pf[it * 2 + 1], acc[ct][it]);   \
      }                                                                      \
    __builtin_amdgcn_s_setprio(0);                                           \
  }

    for (int n2 = 0; n2 < 32; ++n2) {
        PV_ITER(2 * n2,     kfA, kfB);
        PV_ITER(2 * n2 + 1, kfB, kfA);
    }
#undef PV_ITER

    // publish l_i (accsum rows identical = full sum over j), then scale+write
    if (sm && g == 0) Llds[wave * 16 + ln] = accsum[0];
    __syncthreads();
    const float gam = gamma[0];
    float sc4[4];
#pragma unroll
    for (int it = 0; it < 4; ++it) sc4[it] = gam / Llds[it * 16 + ln];

#pragma unroll
    for (int ct = 0; ct < 2; ++ct)
#pragma unroll
        for (int it = 0; it < 4; ++it)
#pragma unroll
            for (int r = 0; r < 4; ++r) {
                const int c = wave * 32 + ct * 16 + g * 4 + r;
                const int i = i_base + it * 16 + ln;
                const size_t idx = ((size_t)b * CFEAT + c) * N_PIX + i;
                out[idx] = sc4[it] * acc[ct][it][r] + features[idx];
            }
#undef STAGE
#undef LOADK
#undef PWRITE
}

// ---------------------------------------------------------------------------
extern "C" void kernel_launch(void* const* d_in, const int* in_sizes, int n_in,
                              void* d_out, int out_size, void* d_ws, size_t ws_size,
                              hipStream_t stream) {
    const float* features   = (const float*)d_in[0];
    const float* conditions = (const float*)d_in[1];
    const float* Wq  = (const float*)d_in[2];
    const float* bq  = (const float*)d_in[3];
    const float* Wk  = (const float*)d_in[4];
    const float* bk  = (const float*)d_in[5];
    const float* Wv  = (const float*)d_in[6];
    const float* bv  = (const float*)d_in[7];
    const float* gam = (const float*)d_in[8];
    float* out = (float*)d_out;

    // ws (bf16): Qt 1MB | Kt 1MB | V 8MB
    bf16_t* Qt = (bf16_t*)d_ws;
    bf16_t* Kt = Qt + (size_t)NBATCH * N_PIX * CKEY;
    bf16_t* Vw = Kt + (size_t)NBATCH * N_PIX * CKEY;
    // XT (bf16 [b][n][c]) staged in d_out (16 MB, exact fit); pv overwrites it.
    bf16_t* XTc = (bf16_t*)d_out;
    bf16_t* XTf = XTc + (size_t)NBATCH * N_PIX * CFEAT;

    prep_kernel<<<dim3(2048, 1, 1), 256, 0, stream>>>(conditions, features, XTc, XTf);
    proj_kernel<<<dim3(1024, 1, 1), 256, 0, stream>>>(
        Wq, bq, Wk, bk, Wv, bv, XTc, XTf, Qt, Kt, Vw);
    pv_kernel<<<dim3(64, NBATCH, 1), 512, 0, stream>>>(
        Qt, Kt, Vw, features, gam, out);
}